// Round 5
// baseline (287.875 us; speedup 1.0000x reference)
//
#include <hip/hip_runtime.h>
#include <stdint.h>

#define NBLK 128           // sequence blocks
#define KDIM 512

typedef __attribute__((ext_vector_type(8))) short short8;
typedef __attribute__((ext_vector_type(4))) float f32x4;
typedef unsigned short u16;

__device__ __forceinline__ u16 f2bf(float f) {
  unsigned u = __float_as_uint(f);
  u = u + 0x7fffu + ((u >> 16) & 1u);
  return (u16)(u >> 16);
}

__device__ __forceinline__ short8 pack8(float4 a, float4 b) {
  short8 r;
  r[0] = (short)f2bf(a.x); r[1] = (short)f2bf(a.y);
  r[2] = (short)f2bf(a.z); r[3] = (short)f2bf(a.w);
  r[4] = (short)f2bf(b.x); r[5] = (short)f2bf(b.y);
  r[6] = (short)f2bf(b.z); r[7] = (short)f2bf(b.w);
  return r;
}

__device__ __forceinline__ void g2l16(const void* g, void* l) {
  __builtin_amdgcn_global_load_lds(
      (__attribute__((address_space(1))) void*)(g),
      (__attribute__((address_space(3))) void*)(l), 16, 0, 0);
}

// ---------------- K0b: weight prep ----------------
__global__ void prep_weights(const float* __restrict__ qw, const float* __restrict__ kw,
                             const float* __restrict__ vw, const float* __restrict__ ow,
                             u16* __restrict__ wqt, u16* __restrict__ wkt,
                             u16* __restrict__ wvt, u16* __restrict__ owb) {
  int t = blockIdx.x * 256 + threadIdx.x;    // 0..65535
  int y = blockIdx.y;
  if (y < 3) {
    const float* w = (y == 0) ? qw : (y == 1) ? kw : vw;
    u16* dstp = (y == 0) ? wqt : (y == 1) ? wkt : wvt;
    int c = t >> 7;              // 0..511
    int e4 = (t & 127) * 4;
    int h = c >> 6, d = c & 63;
    const float* base = w + h * (512 * 64) + d;
    ushort4 r;
    r.x = f2bf(base[(e4 + 0) * 64]);
    r.y = f2bf(base[(e4 + 1) * 64]);
    r.z = f2bf(base[(e4 + 2) * 64]);
    r.w = f2bf(base[(e4 + 3) * 64]);
    *(ushort4*)(dstp + c * 512 + e4) = r;
  } else {
    float4 val = *(const float4*)(ow + t * 4);
    ushort4 r;
    r.x = f2bf(val.x); r.y = f2bf(val.y); r.z = f2bf(val.z); r.w = f2bf(val.w);
    *(ushort4*)(owb + t * 4) = r;
  }
}

// ---------------- GEMM core: C[M][N] = A[M][K] * BT[N][K]^T (bf16 compute, K=512) ----
// 2-deep software pipeline: register staging sets x2, LDS buffers x2, ONE barrier
// per k-iteration. Loads for tile i+2 issue at top of iter i; ds_write of tile i+1
// (loaded a full iteration ago) after the MFMA phase -> vmcnt waits are ~free.
// LDS rows 32 u16 (4 chunks of 16B); chunk g stored at p = g ^ ((row>>1)&3).
// sh layout: A bufs [0,8K) u16 units [0..4095]+[4096..8191]; B bufs [8192..16383].
// MODE 0: u16 out [b][h][s][d], bias by n. MODE 1: u16 out V^T [b][hd][s], bias by m.
// MODE 2: fp32 out (s,b,e), bias by n.
template <int MODE, bool AF32, bool BF32>
__device__ __forceinline__ void gemm_core(const void* __restrict__ Av, const void* __restrict__ Bv,
                                          const float* __restrict__ bias, void* __restrict__ dstv,
                                          int tileM, int tileN, u16* sh) {
  const int t = threadIdx.x;
  const int lane = t & 63, w = t >> 6;
  const int l15 = lane & 15, quad = lane >> 4;
  const int wm = w >> 1, wn = w & 1;

  f32x4 acc[4][4];
#pragma unroll
  for (int i = 0; i < 4; ++i)
#pragma unroll
    for (int j = 0; j < 4; ++j) acc[i][j] = (f32x4){0.f, 0.f, 0.f, 0.f};

  // staging thread map: row r = t>>1 (0..127), k-half h = t&1 (16 elems)
  const int r = t >> 1, h = t & 1;
  const int swz = (r >> 1) & 3;

  const float* gA32 = nullptr; const u16* gA16 = nullptr;
  {
    const int grow = tileM + r;
    if (AF32) {
      const int b = grow >> 13, s = grow & 8191;
      gA32 = (const float*)Av + (size_t)(s * 2 + b) * 512 + h * 16;
    } else {
      gA16 = (const u16*)Av + (size_t)grow * 512 + h * 16;
    }
  }
  const float* gB32 = nullptr; const u16* gB16 = nullptr;
  {
    const int grow = tileN + r;
    if (BF32) {
      const int b = grow >> 13, s = grow & 8191;
      gB32 = (const float*)Bv + (size_t)(s * 2 + b) * 512 + h * 16;
    } else {
      gB16 = (const u16*)Bv + (size_t)grow * 512 + h * 16;
    }
  }

  u16* ldsA = sh + r * 32;          // + buf*4096 at use
  u16* ldsB = sh + 8192 + r * 32;
  const int p0 = ((2 * h) ^ swz) << 3;
  const int p1 = ((2 * h + 1) ^ swz) << 3;

  float4 fa[2][4], fb[2][4];
  short8 sa[2][2], sb[2][2];

#define LOAD_TILE(k0, set)                                        \
  do {                                                            \
    if (AF32) {                                                   \
      fa[set][0] = *(const float4*)(gA32 + (k0));                 \
      fa[set][1] = *(const float4*)(gA32 + (k0) + 4);             \
      fa[set][2] = *(const float4*)(gA32 + (k0) + 8);             \
      fa[set][3] = *(const float4*)(gA32 + (k0) + 12);            \
    } else {                                                      \
      sa[set][0] = *(const short8*)(gA16 + (k0));                 \
      sa[set][1] = *(const short8*)(gA16 + (k0) + 8);             \
    }                                                             \
    if (BF32) {                                                   \
      fb[set][0] = *(const float4*)(gB32 + (k0));                 \
      fb[set][1] = *(const float4*)(gB32 + (k0) + 4);             \
      fb[set][2] = *(const float4*)(gB32 + (k0) + 8);             \
      fb[set][3] = *(const float4*)(gB32 + (k0) + 12);            \
    } else {                                                      \
      sb[set][0] = *(const short8*)(gB16 + (k0));                 \
      sb[set][1] = *(const short8*)(gB16 + (k0) + 8);             \
    }                                                             \
  } while (0)

#define STORE_TILE(set, buf)                                      \
  do {                                                            \
    u16* la = ldsA + (buf) * 4096;                                \
    u16* lb = ldsB + (buf) * 4096;                                \
    if (AF32) {                                                   \
      *(short8*)(la + p0) = pack8(fa[set][0], fa[set][1]);        \
      *(short8*)(la + p1) = pack8(fa[set][2], fa[set][3]);        \
    } else {                                                      \
      *(short8*)(la + p0) = sa[set][0];                           \
      *(short8*)(la + p1) = sa[set][1];                           \
    }                                                             \
    if (BF32) {                                                   \
      *(short8*)(lb + p0) = pack8(fb[set][0], fb[set][1]);        \
      *(short8*)(lb + p1) = pack8(fb[set][2], fb[set][3]);        \
    } else {                                                      \
      *(short8*)(lb + p0) = sb[set][0];                           \
      *(short8*)(lb + p1) = sb[set][1];                           \
    }                                                             \
  } while (0)

  // prologue: tile0 -> lds buf0; tile1 loads in flight
  LOAD_TILE(0, 0);
  STORE_TILE(0, 0);
  LOAD_TILE(32, 1);
  __syncthreads();

#pragma unroll
  for (int i = 0; i < 16; ++i) {
    const int cur = i & 1;
    // prefetch tile i+2 into the register set just freed (set i&1)
    if (i < 14) LOAD_TILE((i + 2) * 32, cur);

    const u16* Ab = sh + cur * 4096;
    const u16* Bb = sh + 8192 + cur * 4096;
    short8 af[4], bf[4];
#pragma unroll
    for (int mt = 0; mt < 4; ++mt) {
      const int ra = wm * 64 + mt * 16 + l15;
      af[mt] = *(const short8*)(Ab + ra * 32 + ((quad ^ ((ra >> 1) & 3)) << 3));
    }
#pragma unroll
    for (int nt = 0; nt < 4; ++nt) {
      const int rb = wn * 64 + nt * 16 + l15;
      bf[nt] = *(const short8*)(Bb + rb * 32 + ((quad ^ ((rb >> 1) & 3)) << 3));
    }
#pragma unroll
    for (int mt = 0; mt < 4; ++mt)
#pragma unroll
      for (int nt = 0; nt < 4; ++nt)
        acc[mt][nt] = __builtin_amdgcn_mfma_f32_16x16x32_bf16(af[mt], bf[nt], acc[mt][nt], 0, 0, 0);

    // stage tile i+1 (its loads issued a full iteration ago)
    if (i < 15) STORE_TILE((i + 1) & 1, (i + 1) & 1);
    __syncthreads();
  }
#undef LOAD_TILE
#undef STORE_TILE

  if (MODE == 0 || MODE == 1) {
    // C-tile (u16, 128x128) -> LDS with chunk swizzle, then coalesced 16B stores
#pragma unroll
    for (int mt = 0; mt < 4; ++mt)
#pragma unroll
      for (int nt = 0; nt < 4; ++nt)
#pragma unroll
        for (int rr = 0; rr < 4; ++rr) {
          const int lrow = wm * 64 + mt * 16 + quad * 4 + rr;
          const int col = wn * 64 + nt * 16 + l15;
          float v = acc[mt][nt][rr] + (MODE == 0 ? bias[tileN + col] : bias[tileM + lrow]);
          const int ch = col >> 3;
          sh[lrow * 128 + ((ch ^ (lrow & 7)) << 3) + (col & 7)] = f2bf(v);
        }
    __syncthreads();
#pragma unroll
    for (int p = 0; p < 8; ++p) {
      const int idx = p * 256 + t;
      const int row = idx >> 4, c = idx & 15;
      short8 vch = *(const short8*)(sh + row * 128 + ((c ^ (row & 7)) << 3));
      if (MODE == 0) {
        const int m = tileM + row, b = m >> 13, s = m & 8191;
        const int n0 = tileN + c * 8, hh = n0 >> 6, d = n0 & 63;
        *(short8*)((u16*)dstv + (((b * 8 + hh) * 8192 + s) * 64 + d)) = vch;
      } else {
        const int hd = tileM + row;
        const int n0 = tileN + c * 8, b = n0 >> 13, s = n0 & 8191;
        *(short8*)((u16*)dstv + ((b * 512 + hd) * 8192 + s)) = vch;
      }
    }
  } else {
    // fp32 C-tile in two 64-row halves (32 KB each)
    float* Cf = (float*)sh;   // 8192 floats
#pragma unroll
    for (int half = 0; half < 2; ++half) {
      if (wm == half) {
#pragma unroll
        for (int mt = 0; mt < 4; ++mt)
#pragma unroll
          for (int nt = 0; nt < 4; ++nt)
#pragma unroll
            for (int rr = 0; rr < 4; ++rr) {
              const int lrow = mt * 16 + quad * 4 + rr;
              const int col = wn * 64 + nt * 16 + l15;
              float v = acc[mt][nt][rr] + bias[tileN + col];
              const int ch = col >> 2;
              Cf[lrow * 128 + ((ch ^ ((lrow & 7) << 2)) << 2) + (col & 3)] = v;
            }
      }
      __syncthreads();
#pragma unroll
      for (int p = 0; p < 8; ++p) {
        const int idx = p * 256 + t;
        const int row = idx >> 5, c = idx & 31;
        float4 v4 = *(const float4*)(Cf + row * 128 + ((c ^ ((row & 7) << 2)) << 2));
        const int m = tileM + half * 64 + row;
        const int s = m & 8191, b = m >> 13;
        *(float4*)((float*)dstv + ((s * 2 + b) * 512 + tileN + c * 4)) = v4;
      }
      __syncthreads();
    }
  }
}

// merged QKV projection: z=0 Q, z=1 K, z=2 V^T. XCD swizzle: blocks sharing
// A-rows share an XCD L2.
__global__ __launch_bounds__(256, 3)
void gemm_qkv(const float* __restrict__ q, const float* __restrict__ k, const float* __restrict__ v,
              const u16* __restrict__ WqT, const u16* __restrict__ WkT, const u16* __restrict__ WvT,
              const float* __restrict__ qbi, const float* __restrict__ kbi, const float* __restrict__ vbi,
              u16* __restrict__ Qb, u16* __restrict__ Kb, u16* __restrict__ Vt) {
  __shared__ u16 sh[16384];
  const int id = blockIdx.x + blockIdx.y * 4;
  const int xs = (id >> 3) & 3;
  const int ys = (id & 7) * 16 + (id >> 5);
  const int z = blockIdx.z;
  if (z == 0)      gemm_core<0, true, false>(q, WqT, qbi, Qb, ys * 128, xs * 128, sh);
  else if (z == 1) gemm_core<0, true, false>(k, WkT, kbi, Kb, ys * 128, xs * 128, sh);
  else             gemm_core<1, false, true>(WvT, v, vbi, Vt, xs * 128, ys * 128, sh);
}

__global__ __launch_bounds__(256, 3)
void gemm_out_k(const u16* __restrict__ AO, const u16* __restrict__ OW,
                const float* __restrict__ ob, float* __restrict__ out) {
  __shared__ u16 sh[16384];
  const int id = blockIdx.x + blockIdx.y * 4;
  const int xs = (id >> 3) & 3;
  const int ys = (id & 7) * 16 + (id >> 5);
  gemm_core<2, false, false>(AO, OW, ob, out, ys * 128, xs * 128, sh);
}

// ---------------- K2: block-sparse attention (double-buffered K/V staging) --------
// grid 2048x1. bh = blk&15 (XCD L2 locality), nb = blk>>4.
// Qb/Kb: [b][h][s][d] bf16, Vt: [b][h][d][s] bf16. AO out: [b*8192+s][h*64+d] bf16.
// g2l prefetch of chunk m+1 issues before compute of chunk m -> barrier drain hidden.
__global__ __launch_bounds__(256, 4)
void attn(const u16* __restrict__ Qb, const u16* __restrict__ Kb,
          const u16* __restrict__ Vt, const int* __restrict__ ridx,
          u16* __restrict__ AO) {
  __shared__ u16 Ks[2][64 * 64];   // [key][d], 16B-chunk XOR swizzle (r&7)
  __shared__ u16 Vs[2][64 * 64];   // [d][key]
  __shared__ u16 Ps[64 * 64];      // [q][key], wave-private rows
  const int blk = blockIdx.x;
  const int bh = blk & 15, nb = blk >> 4;
  const int b = bh >> 3, h = bh & 7;
  const int t = threadIdx.x, lane = t & 63, w = t >> 6;
  const int l15 = lane & 15, quad = lane >> 4;

  int bidx[8];
  bidx[0] = 0; bidx[1] = 1;
  bidx[2] = (nb + NBLK - 1) & (NBLK - 1);
  bidx[3] = nb;
  bidx[4] = (nb + 1) & (NBLK - 1);
  bidx[5] = ridx[nb * 3 + 0];
  bidx[6] = ridx[nb * 3 + 1];
  bidx[7] = ridx[nb * 3 + 2];

  const u16* qrow = Qb + (bh * 8192 + nb * 64 + w * 16 + l15) * 64;
  short8 aq0 = *(const short8*)(qrow + quad * 8);
  short8 aq1 = *(const short8*)(qrow + 32 + quad * 8);

  const int s0 = t, s1 = t + 256;
  const int r0 = s0 >> 3, c0 = (s0 & 7) ^ (r0 & 7);
  const int r1 = s1 >> 3, c1 = (s1 & 7) ^ (r1 & 7);
  const u16* Kbase = Kb + bh * 8192 * 64;
  const u16* Vbase = Vt + (bh * 64) * 8192;

#define STAGE_KV(m, buf)                                               \
  do {                                                                 \
    const int kb0 = bidx[m] * 64;                                      \
    g2l16(Kbase + (kb0 + r0) * 64 + c0 * 8, Ks[buf] + s0 * 8);         \
    g2l16(Kbase + (kb0 + r1) * 64 + c1 * 8, Ks[buf] + s1 * 8);         \
    g2l16(Vbase + r0 * 8192 + kb0 + c0 * 8, Vs[buf] + s0 * 8);         \
    g2l16(Vbase + r1 * 8192 + kb0 + c1 * 8, Vs[buf] + s1 * 8);         \
  } while (0)

  f32x4 oacc[4];
#pragma unroll
  for (int i = 0; i < 4; ++i) oacc[i] = (f32x4){0.f, 0.f, 0.f, 0.f};
  float lsum[4] = {0.f, 0.f, 0.f, 0.f};

  STAGE_KV(0, 0);
  __syncthreads();

#pragma unroll
  for (int m = 0; m < 8; ++m) {
    const int cur = m & 1;
    if (m < 7) STAGE_KV(m + 1, cur ^ 1);   // in flight across this chunk's compute

    f32x4 s[4];
#pragma unroll
    for (int i = 0; i < 4; ++i) s[i] = (f32x4){0.f, 0.f, 0.f, 0.f};
#pragma unroll
    for (int nt = 0; nt < 4; ++nt) {
      const int key = nt * 16 + l15;
      const u16* kr = Ks[cur] + key * 64;
      short8 bk0 = *(const short8*)(kr + ((quad ^ (key & 7)) << 3));
      short8 bk1 = *(const short8*)(kr + (((4 + quad) ^ (key & 7)) << 3));
      s[nt] = __builtin_amdgcn_mfma_f32_16x16x32_bf16(aq0, bk0, s[nt], 0, 0, 0);
      s[nt] = __builtin_amdgcn_mfma_f32_16x16x32_bf16(aq1, bk1, s[nt], 0, 0, 0);
    }

#pragma unroll
    for (int nt = 0; nt < 4; ++nt) {
      const int key = nt * 16 + l15;
      const int cp = key >> 3;
#pragma unroll
      for (int rr = 0; rr < 4; ++rr) {
        float p = __expf(s[nt][rr] * 0.125f);
        lsum[rr] += p;
        const int q = w * 16 + quad * 4 + rr;
        Ps[q * 64 + (((cp ^ (q & 7)) << 3) | (key & 7))] = f2bf(p);
      }
    }

    const int q2 = w * 16 + l15;
    const u16* pr = Ps + q2 * 64;
    short8 ap0 = *(const short8*)(pr + ((quad ^ (q2 & 7)) << 3));
    short8 ap1 = *(const short8*)(pr + (((4 + quad) ^ (q2 & 7)) << 3));
#pragma unroll
    for (int nt = 0; nt < 4; ++nt) {
      const int d = nt * 16 + l15;
      const u16* vr = Vs[cur] + d * 64;
      short8 bv0 = *(const short8*)(vr + ((quad ^ (d & 7)) << 3));
      short8 bv1 = *(const short8*)(vr + (((4 + quad) ^ (d & 7)) << 3));
      oacc[nt] = __builtin_amdgcn_mfma_f32_16x16x32_bf16(ap0, bv0, oacc[nt], 0, 0, 0);
      oacc[nt] = __builtin_amdgcn_mfma_f32_16x16x32_bf16(ap1, bv1, oacc[nt], 0, 0, 0);
    }
    __syncthreads();
  }
#undef STAGE_KV

#pragma unroll
  for (int msk = 1; msk < 16; msk <<= 1)
#pragma unroll
    for (int rr = 0; rr < 4; ++rr) lsum[rr] += __shfl_xor(lsum[rr], msk, 64);
  float inv[4];
#pragma unroll
  for (int rr = 0; rr < 4; ++rr) inv[rr] = __builtin_amdgcn_rcpf(lsum[rr]);

#pragma unroll
  for (int nt = 0; nt < 4; ++nt) {
    const int cc = h * 64 + nt * 16 + l15;
#pragma unroll
    for (int rr = 0; rr < 4; ++rr) {
      const int s = nb * 64 + w * 16 + quad * 4 + rr;
      AO[(b * 8192 + s) * 512 + cc] = f2bf(oacc[nt][rr] * inv[rr]);
    }
  }
}

// ---------------- launch ----------------
extern "C" void kernel_launch(void* const* d_in, const int* in_sizes, int n_in,
                              void* d_out, int out_size, void* d_ws, size_t ws_size,
                              hipStream_t stream) {
  const float* q   = (const float*)d_in[0];
  const float* k   = (const float*)d_in[1];
  const float* v   = (const float*)d_in[2];
  const float* qw  = (const float*)d_in[3];
  const float* kw  = (const float*)d_in[4];
  const float* vw  = (const float*)d_in[5];
  const float* qbi = (const float*)d_in[6];
  const float* kbi = (const float*)d_in[7];
  const float* vbi = (const float*)d_in[8];
  const float* ow  = (const float*)d_in[9];
  const float* ob  = (const float*)d_in[10];
  const int*   ri  = (const int*)d_in[11];

  char* ws = (char*)d_ws;
  const size_t MB1 = 1024 * 1024;
  u16* Qb   = (u16*)(ws + 0);
  u16* Kb   = (u16*)(ws + 16 * MB1);
  u16* Vt   = (u16*)(ws + 32 * MB1);
  u16* AO   = (u16*)(ws + 48 * MB1);
  u16* WqT  = (u16*)(ws + 64 * MB1);
  u16* WkT  = (u16*)(ws + 64 * MB1 + 512 * 1024);
  u16* WvT  = (u16*)(ws + 65 * MB1);
  u16* OW   = (u16*)(ws + 65 * MB1 + 512 * 1024);

  prep_weights<<<dim3(256, 4), 256, 0, stream>>>(qw, kw, vw, ow, WqT, WkT, WvT, OW);
  gemm_qkv<<<dim3(4, 128, 3), 256, 0, stream>>>(q, k, v, WqT, WkT, WvT,
                                                qbi, kbi, vbi, Qb, Kb, Vt);
  attn<<<2048, 256, 0, stream>>>(Qb, Kb, Vt, ri, AO);
  gemm_out_k<<<dim3(4, 128), 256, 0, stream>>>(AO, OW, ob, (float*)d_out);
}

// Round 6
// 250.312 us; speedup vs baseline: 1.1501x; 1.1501x over previous
//
#include <hip/hip_runtime.h>
#include <stdint.h>

#define NBLK 128           // sequence blocks
#define KDIM 512

typedef __attribute__((ext_vector_type(8))) short short8;
typedef __attribute__((ext_vector_type(4))) float f32x4;
typedef unsigned short u16;

__device__ __forceinline__ u16 f2bf(float f) {
  unsigned u = __float_as_uint(f);
  u = u + 0x7fffu + ((u >> 16) & 1u);
  return (u16)(u >> 16);
}

// round-half-up bf16 (1 fewer op than RNE; differs only on exact ties)
__device__ __forceinline__ short8 pack_ru(f32x4 a, f32x4 b) {
  short8 r;
#pragma unroll
  for (int i = 0; i < 4; ++i) r[i] = (short)((__float_as_uint(a[i]) + 0x8000u) >> 16);
#pragma unroll
  for (int i = 0; i < 4; ++i) r[4 + i] = (short)((__float_as_uint(b[i]) + 0x8000u) >> 16);
  return r;
}

__device__ __forceinline__ void g2l16(const void* g, void* l) {
  __builtin_amdgcn_global_load_lds(
      (__attribute__((address_space(1))) void*)(g),
      (__attribute__((address_space(3))) void*)(l), 16, 0, 0);
}

// ---------------- K0b: weight prep ----------------
__global__ void prep_weights(const float* __restrict__ qw, const float* __restrict__ kw,
                             const float* __restrict__ vw, const float* __restrict__ ow,
                             u16* __restrict__ wqt, u16* __restrict__ wkt,
                             u16* __restrict__ wvt, u16* __restrict__ owb) {
  int t = blockIdx.x * 256 + threadIdx.x;    // 0..65535
  int y = blockIdx.y;
  if (y < 3) {
    const float* w = (y == 0) ? qw : (y == 1) ? kw : vw;
    u16* dstp = (y == 0) ? wqt : (y == 1) ? wkt : wvt;
    int c = t >> 7;              // 0..511
    int e4 = (t & 127) * 4;
    int h = c >> 6, d = c & 63;
    const float* base = w + h * (512 * 64) + d;
    ushort4 r;
    r.x = f2bf(base[(e4 + 0) * 64]);
    r.y = f2bf(base[(e4 + 1) * 64]);
    r.z = f2bf(base[(e4 + 2) * 64]);
    r.w = f2bf(base[(e4 + 3) * 64]);
    *(ushort4*)(dstp + c * 512 + e4) = r;
  } else {
    float4 val = *(const float4*)(ow + t * 4);
    ushort4 r;
    r.x = f2bf(val.x); r.y = f2bf(val.y); r.z = f2bf(val.z); r.w = f2bf(val.w);
    *(ushort4*)(owb + t * 4) = r;
  }
}

// ---------------- GEMM core: C[M][N] = A[M][K] * BT[N][K]^T (bf16 MFMA, K=512) ------
// Round-2 proven structure: g2l16 DMA staging, 2 barriers per k-step.
// fp32 sides (activations in (s,b,e) interleaved layout) are staged AS FP32 via
// g2l16 (16 KB tile, 8 chunks/row, swizzle c^(r&7)) and packed to bf16 at
// fragment-read time. bf16 sides: 8 KB tile, 4 chunks/row, swizzle c^((r>>1)&3)
// (phase advances every 2 rows for 64-B rows) -> conflict-free b128 reads.
// MODE 0: u16 out [b][h][s][d], bias by n. MODE 1: u16 out V^T [b][hd][s], bias by m.
// MODE 2: fp32 out (s,b,e), bias by n.
template <int MODE, bool AF32, bool BF32>
__device__ __forceinline__ void gemm_core(const void* __restrict__ Av, const void* __restrict__ Bv,
                                          const float* __restrict__ bias, void* __restrict__ dstv,
                                          int tileM, int tileN, u16* sh) {
  const int t = threadIdx.x;
  const int lane = t & 63, w = t >> 6;
  const int l15 = lane & 15, quad = lane >> 4;
  const int wm = w >> 1, wn = w & 1;
  const int BOFF = AF32 ? 8192 : 4096;   // u16 units

  f32x4 acc[4][4];
#pragma unroll
  for (int i = 0; i < 4; ++i)
#pragma unroll
    for (int j = 0; j < 4; ++j) acc[i][j] = (f32x4){0.f, 0.f, 0.f, 0.f};

  // ---- DMA source pointers (element units; k advances by k0 elements) ----
  const float* aSrcF[4]; const u16* aSrcH[2];
  if (AF32) {
#pragma unroll
    for (int i = 0; i < 4; ++i) {
      const int s = t + i * 256;                    // LDS 16B-slot
      const int r = s >> 3, g = (s & 7) ^ (r & 7);  // row, source chunk
      const int grow = tileM + r;
      const int bb = grow >> 13, ss = grow & 8191;
      aSrcF[i] = (const float*)Av + (size_t)(ss * 2 + bb) * 512 + g * 4;
    }
  } else {
#pragma unroll
    for (int i = 0; i < 2; ++i) {
      const int s = t + i * 256;
      const int r = s >> 2, g = (s & 3) ^ ((r >> 1) & 3);
      aSrcH[i] = (const u16*)Av + (size_t)(tileM + r) * 512 + g * 8;
    }
  }
  const float* bSrcF[4]; const u16* bSrcH[2];
  if (BF32) {
#pragma unroll
    for (int i = 0; i < 4; ++i) {
      const int s = t + i * 256;
      const int r = s >> 3, g = (s & 7) ^ (r & 7);
      const int grow = tileN + r;
      const int bb = grow >> 13, ss = grow & 8191;
      bSrcF[i] = (const float*)Bv + (size_t)(ss * 2 + bb) * 512 + g * 4;
    }
  } else {
#pragma unroll
    for (int i = 0; i < 2; ++i) {
      const int s = t + i * 256;
      const int r = s >> 2, g = (s & 3) ^ ((r >> 1) & 3);
      bSrcH[i] = (const u16*)Bv + (size_t)(tileN + r) * 512 + g * 8;
    }
  }

  for (int k0 = 0; k0 < KDIM; k0 += 32) {
    __syncthreads();
    if (AF32) {
#pragma unroll
      for (int i = 0; i < 4; ++i) g2l16(aSrcF[i] + k0, sh + (t + i * 256) * 8);
    } else {
#pragma unroll
      for (int i = 0; i < 2; ++i) g2l16(aSrcH[i] + k0, sh + (t + i * 256) * 8);
    }
    if (BF32) {
#pragma unroll
      for (int i = 0; i < 4; ++i) g2l16(bSrcF[i] + k0, sh + BOFF + (t + i * 256) * 8);
    } else {
#pragma unroll
      for (int i = 0; i < 2; ++i) g2l16(bSrcH[i] + k0, sh + BOFF + (t + i * 256) * 8);
    }
    __syncthreads();

    short8 af[4], bf[4];
#pragma unroll
    for (int mt = 0; mt < 4; ++mt) {
      const int ra = wm * 64 + mt * 16 + l15;
      if (AF32) {
        const float* Af = (const float*)sh;
        f32x4 f0 = *(const f32x4*)(Af + ra * 32 + (((2 * quad) ^ (ra & 7)) << 2));
        f32x4 f1 = *(const f32x4*)(Af + ra * 32 + (((2 * quad + 1) ^ (ra & 7)) << 2));
        af[mt] = pack_ru(f0, f1);
      } else {
        af[mt] = *(const short8*)(sh + ra * 32 + ((quad ^ ((ra >> 1) & 3)) << 3));
      }
    }
#pragma unroll
    for (int nt = 0; nt < 4; ++nt) {
      const int rb = wn * 64 + nt * 16 + l15;
      if (BF32) {
        const float* Bf = (const float*)(sh + BOFF);
        f32x4 f0 = *(const f32x4*)(Bf + rb * 32 + (((2 * quad) ^ (rb & 7)) << 2));
        f32x4 f1 = *(const f32x4*)(Bf + rb * 32 + (((2 * quad + 1) ^ (rb & 7)) << 2));
        bf[nt] = pack_ru(f0, f1);
      } else {
        bf[nt] = *(const short8*)(sh + BOFF + rb * 32 + ((quad ^ ((rb >> 1) & 3)) << 3));
      }
    }
#pragma unroll
    for (int mt = 0; mt < 4; ++mt)
#pragma unroll
      for (int nt = 0; nt < 4; ++nt)
        acc[mt][nt] = __builtin_amdgcn_mfma_f32_16x16x32_bf16(af[mt], bf[nt], acc[mt][nt], 0, 0, 0);
  }
  __syncthreads();   // staging LDS fully consumed before epilogue reuse

  if (MODE == 0 || MODE == 1) {
    // C-tile (u16, 128x128) -> LDS with chunk swizzle, then coalesced 16B stores
#pragma unroll
    for (int mt = 0; mt < 4; ++mt)
#pragma unroll
      for (int nt = 0; nt < 4; ++nt)
#pragma unroll
        for (int rr = 0; rr < 4; ++rr) {
          const int lrow = wm * 64 + mt * 16 + quad * 4 + rr;
          const int col = wn * 64 + nt * 16 + l15;
          float v = acc[mt][nt][rr] + (MODE == 0 ? bias[tileN + col] : bias[tileM + lrow]);
          const int ch = col >> 3;
          sh[lrow * 128 + ((ch ^ (lrow & 7)) << 3) + (col & 7)] = f2bf(v);
        }
    __syncthreads();
#pragma unroll
    for (int p = 0; p < 8; ++p) {
      const int idx = p * 256 + t;
      const int row = idx >> 4, c = idx & 15;
      short8 vch = *(const short8*)(sh + row * 128 + ((c ^ (row & 7)) << 3));
      if (MODE == 0) {
        const int m = tileM + row, b = m >> 13, s = m & 8191;
        const int n0 = tileN + c * 8, hh = n0 >> 6, d = n0 & 63;
        *(short8*)((u16*)dstv + (((b * 8 + hh) * 8192 + s) * 64 + d)) = vch;
      } else {
        const int hd = tileM + row;
        const int n0 = tileN + c * 8, b = n0 >> 13, s = n0 & 8191;
        *(short8*)((u16*)dstv + ((b * 512 + hd) * 8192 + s)) = vch;
      }
    }
  } else {
    // fp32 C-tile in two 64-row halves (32 KB each)
    float* Cf = (float*)sh;   // 8192 floats
#pragma unroll
    for (int half = 0; half < 2; ++half) {
      if (wm == half) {
#pragma unroll
        for (int mt = 0; mt < 4; ++mt)
#pragma unroll
          for (int nt = 0; nt < 4; ++nt)
#pragma unroll
            for (int rr = 0; rr < 4; ++rr) {
              const int lrow = mt * 16 + quad * 4 + rr;
              const int col = wn * 64 + nt * 16 + l15;
              float v = acc[mt][nt][rr] + bias[tileN + col];
              const int ch = col >> 2;
              Cf[lrow * 128 + ((ch ^ ((lrow & 7) << 2)) << 2) + (col & 3)] = v;
            }
      }
      __syncthreads();
#pragma unroll
      for (int p = 0; p < 8; ++p) {
        const int idx = p * 256 + t;
        const int row = idx >> 5, c = idx & 31;
        float4 v4 = *(const float4*)(Cf + row * 128 + ((c ^ ((row & 7) << 2)) << 2));
        const int m = tileM + half * 64 + row;
        const int s = m & 8191, b = m >> 13;
        *(float4*)((float*)dstv + ((s * 2 + b) * 512 + tileN + c * 4)) = v4;
      }
      __syncthreads();
    }
  }
}

// merged QKV projection: z=0 Q, z=1 K, z=2 V^T. XCD swizzle: blocks sharing
// A-rows share an XCD L2. Activations read fp32 directly (conv kernel deleted).
__global__ __launch_bounds__(256, 4)
void gemm_qkv(const float* __restrict__ q, const float* __restrict__ k, const float* __restrict__ v,
              const u16* __restrict__ WqT, const u16* __restrict__ WkT, const u16* __restrict__ WvT,
              const float* __restrict__ qbi, const float* __restrict__ kbi, const float* __restrict__ vbi,
              u16* __restrict__ Qb, u16* __restrict__ Kb, u16* __restrict__ Vt) {
  __shared__ __align__(16) u16 sh[16384];
  const int id = blockIdx.x + blockIdx.y * 4;
  const int xs = (id >> 3) & 3;
  const int ys = (id & 7) * 16 + (id >> 5);
  const int z = blockIdx.z;
  if (z == 0)      gemm_core<0, true, false>(q, WqT, qbi, Qb, ys * 128, xs * 128, sh);
  else if (z == 1) gemm_core<0, true, false>(k, WkT, kbi, Kb, ys * 128, xs * 128, sh);
  else             gemm_core<1, false, true>(WvT, v, vbi, Vt, xs * 128, ys * 128, sh);
}

__global__ __launch_bounds__(256, 4)
void gemm_out_k(const u16* __restrict__ AO, const u16* __restrict__ OW,
                const float* __restrict__ ob, float* __restrict__ out) {
  __shared__ __align__(16) u16 sh[16384];
  const int id = blockIdx.x + blockIdx.y * 4;
  const int xs = (id >> 3) & 3;
  const int ys = (id & 7) * 16 + (id >> 5);
  gemm_core<2, false, false>(AO, OW, ob, out, ys * 128, xs * 128, sh);
}

// ---------------- K2: block-sparse attention (round-2 measured-good form) ---------
// grid 2048x1. bh = blk&15 (XCD L2 locality), nb = blk>>4.
// Qb/Kb: [b][h][s][d] bf16, Vt: [b][h][d][s] bf16. AO out: [b*8192+s][h*64+d] bf16.
__global__ __launch_bounds__(256, 5)
void attn(const u16* __restrict__ Qb, const u16* __restrict__ Kb,
          const u16* __restrict__ Vt, const int* __restrict__ ridx,
          u16* __restrict__ AO) {
  __shared__ u16 Ks[64 * 64];   // [key][d], 16B-chunk XOR swizzle (r&7)
  __shared__ u16 Vs[64 * 64];   // [d][key]
  __shared__ u16 Ps[64 * 64];   // [q][key], wave-private rows
  const int blk = blockIdx.x;
  const int bh = blk & 15, nb = blk >> 4;
  const int b = bh >> 3, h = bh & 7;
  const int t = threadIdx.x, lane = t & 63, w = t >> 6;
  const int l15 = lane & 15, quad = lane >> 4;

  int bidx[8];
  bidx[0] = 0; bidx[1] = 1;
  bidx[2] = (nb + NBLK - 1) & (NBLK - 1);
  bidx[3] = nb;
  bidx[4] = (nb + 1) & (NBLK - 1);
  bidx[5] = ridx[nb * 3 + 0];
  bidx[6] = ridx[nb * 3 + 1];
  bidx[7] = ridx[nb * 3 + 2];

  const u16* qrow = Qb + (bh * 8192 + nb * 64 + w * 16 + l15) * 64;
  short8 aq0 = *(const short8*)(qrow + quad * 8);
  short8 aq1 = *(const short8*)(qrow + 32 + quad * 8);

  const int s0 = t, s1 = t + 256;
  const int r0 = s0 >> 3, c0 = (s0 & 7) ^ (r0 & 7);
  const int r1 = s1 >> 3, c1 = (s1 & 7) ^ (r1 & 7);
  const u16* Kbase = Kb + bh * 8192 * 64;
  const u16* Vbase = Vt + (bh * 64) * 8192;

  f32x4 oacc[4];
#pragma unroll
  for (int i = 0; i < 4; ++i) oacc[i] = (f32x4){0.f, 0.f, 0.f, 0.f};
  float lsum[4] = {0.f, 0.f, 0.f, 0.f};

  for (int m = 0; m < 8; ++m) {
    const int kb0 = bidx[m] * 64;
    __syncthreads();
    g2l16(Kbase + (kb0 + r0) * 64 + c0 * 8, Ks + s0 * 8);
    g2l16(Kbase + (kb0 + r1) * 64 + c1 * 8, Ks + s1 * 8);
    g2l16(Vbase + r0 * 8192 + kb0 + c0 * 8, Vs + s0 * 8);
    g2l16(Vbase + r1 * 8192 + kb0 + c1 * 8, Vs + s1 * 8);
    __syncthreads();

    f32x4 s[4];
#pragma unroll
    for (int i = 0; i < 4; ++i) s[i] = (f32x4){0.f, 0.f, 0.f, 0.f};
#pragma unroll
    for (int nt = 0; nt < 4; ++nt) {
      const int key = nt * 16 + l15;
      const u16* kr = Ks + key * 64;
      short8 bk0 = *(const short8*)(kr + ((quad ^ (key & 7)) << 3));
      short8 bk1 = *(const short8*)(kr + (((4 + quad) ^ (key & 7)) << 3));
      s[nt] = __builtin_amdgcn_mfma_f32_16x16x32_bf16(aq0, bk0, s[nt], 0, 0, 0);
      s[nt] = __builtin_amdgcn_mfma_f32_16x16x32_bf16(aq1, bk1, s[nt], 0, 0, 0);
    }

#pragma unroll
    for (int nt = 0; nt < 4; ++nt) {
      const int key = nt * 16 + l15;
      const int cp = key >> 3;
#pragma unroll
      for (int rr = 0; rr < 4; ++rr) {
        float p = __expf(s[nt][rr] * 0.125f);
        lsum[rr] += p;
        const int q = w * 16 + quad * 4 + rr;
        Ps[q * 64 + (((cp ^ (q & 7)) << 3) | (key & 7))] = f2bf(p);
      }
    }

    const int q2 = w * 16 + l15;
    const u16* pr = Ps + q2 * 64;
    short8 ap0 = *(const short8*)(pr + ((quad ^ (q2 & 7)) << 3));
    short8 ap1 = *(const short8*)(pr + (((4 + quad) ^ (q2 & 7)) << 3));
#pragma unroll
    for (int nt = 0; nt < 4; ++nt) {
      const int d = nt * 16 + l15;
      const u16* vr = Vs + d * 64;
      short8 bv0 = *(const short8*)(vr + ((quad ^ (d & 7)) << 3));
      short8 bv1 = *(const short8*)(vr + (((4 + quad) ^ (d & 7)) << 3));
      oacc[nt] = __builtin_amdgcn_mfma_f32_16x16x32_bf16(ap0, bv0, oacc[nt], 0, 0, 0);
      oacc[nt] = __builtin_amdgcn_mfma_f32_16x16x32_bf16(ap1, bv1, oacc[nt], 0, 0, 0);
    }
  }

#pragma unroll
  for (int msk = 1; msk < 16; msk <<= 1)
#pragma unroll
    for (int rr = 0; rr < 4; ++rr) lsum[rr] += __shfl_xor(lsum[rr], msk, 64);
  float inv[4];
#pragma unroll
  for (int rr = 0; rr < 4; ++rr) inv[rr] = __builtin_amdgcn_rcpf(lsum[rr]);

#pragma unroll
  for (int nt = 0; nt < 4; ++nt) {
    const int cc = h * 64 + nt * 16 + l15;
#pragma unroll
    for (int rr = 0; rr < 4; ++rr) {
      const int s = nb * 64 + w * 16 + quad * 4 + rr;
      AO[(b * 8192 + s) * 512 + cc] = f2bf(oacc[nt][rr] * inv[rr]);
    }
  }
}

// ---------------- launch ----------------
extern "C" void kernel_launch(void* const* d_in, const int* in_sizes, int n_in,
                              void* d_out, int out_size, void* d_ws, size_t ws_size,
                              hipStream_t stream) {
  const float* q   = (const float*)d_in[0];
  const float* k   = (const float*)d_in[1];
  const float* v   = (const float*)d_in[2];
  const float* qw  = (const float*)d_in[3];
  const float* kw  = (const float*)d_in[4];
  const float* vw  = (const float*)d_in[5];
  const float* qbi = (const float*)d_in[6];
  const float* kbi = (const float*)d_in[7];
  const float* vbi = (const float*)d_in[8];
  const float* ow  = (const float*)d_in[9];
  const float* ob  = (const float*)d_in[10];
  const int*   ri  = (const int*)d_in[11];

  char* ws = (char*)d_ws;
  const size_t MB1 = 1024 * 1024;
  u16* Qb   = (u16*)(ws + 0);
  u16* Kb   = (u16*)(ws + 16 * MB1);
  u16* Vt   = (u16*)(ws + 32 * MB1);
  u16* AO   = (u16*)(ws + 48 * MB1);
  u16* WqT  = (u16*)(ws + 64 * MB1);
  u16* WkT  = (u16*)(ws + 64 * MB1 + 512 * 1024);
  u16* WvT  = (u16*)(ws + 65 * MB1);
  u16* OW   = (u16*)(ws + 65 * MB1 + 512 * 1024);

  prep_weights<<<dim3(256, 4), 256, 0, stream>>>(qw, kw, vw, ow, WqT, WkT, WvT, OW);
  gemm_qkv<<<dim3(4, 128, 3), 256, 0, stream>>>(q, k, v, WqT, WkT, WvT,
                                                qbi, kbi, vbi, Qb, Kb, Vt);
  attn<<<2048, 256, 0, stream>>>(Qb, Kb, Vt, ri, AO);
  gemm_out_k<<<dim3(4, 128), 256, 0, stream>>>(AO, OW, ob, (float*)d_out);
}